// Round 9
// baseline (235.192 us; speedup 1.0000x reference)
//
#include <hip/hip_runtime.h>

#define IMG_H 768
#define IMG_W 768
#define N_IMG 32
#define TILE 64
#define HALO 2
#define WTH 16             // wave tile height (output rows per wave)
#define SROWS 20           // staged rows = WTH + 2*HALO
#define LW 68              // staged row width = 64 + 2*HALO
#define INV_LOG2 1.44269504088896340736f

__device__ __forceinline__ float fast_sigmoid(float y) {
    return 1.0f / (1.0f + __expf(-y));
}

// Wave-autonomous pass 1: each wave stages + computes a 64x16 strip with NO
// block-level barrier. pw[wid] is written and read only by wave wid, so the
// only ordering needed is in-wave (compiler lgkmcnt waits + wave_barrier).
__global__ __launch_bounds__(256) void wk_pass1(
    const float* __restrict__ y_d, const float* __restrict__ y_gt,
    float* __restrict__ out, float* __restrict__ sums)
{
    __shared__ float pw[4][SROWS * LW];   // 4 waves x 5440 B = 21.8 KB

    const int tiles_x = IMG_W / TILE;                    // 12
    const int tiles_per_img = tiles_x * (IMG_H / TILE);  // 144
    const int b = blockIdx.x;
    const int img = b / tiles_per_img;
    const int t = b - img * tiles_per_img;
    const int ti = t / tiles_x;
    const int tj = t - ti * tiles_x;
    const int gi0 = ti * TILE, gj0 = tj * TILE;

    const size_t img_off = (size_t)img * IMG_H * IMG_W;
    const float* __restrict__ yimg = y_d + img_off;
    const float* __restrict__ gimg = y_gt + img_off;
    float* __restrict__ oimg = out + img_off;

    const int tid  = threadIdx.x;
    const int wid  = tid >> 6;         // wave 0..3
    const int lane = tid & 63;
    const int cg   = lane & 15;        // col group 0..15
    const int rg   = lane >> 4;        // row group 0..3
    const int c0i  = cg << 2;          // col base within tile 0..60
    const int rb   = rg << 2;          // row base within wave strip 0..12
    const int wy0  = gi0 + wid * WTH;  // wave's first output row (global)
    const int gj   = gj0 + c0i;

    float* __restrict__ pbuf = pw[wid];

    // ---- stage (a): own 4x4 block (always in-bounds; tiles partition img).
    // p -> pw rows 2+rb..5+rb; ent + p kept in registers.
    // ent = 1 + (p*y - softplus(y))/ln2, softplus = max(y,0)+log(1+e^-|y|).
    float4 pv4[4], ev4[4];
#pragma unroll
    for (int r = 0; r < 4; ++r) {
        float4 y4 = *reinterpret_cast<const float4*>(
            &yimg[(size_t)(wy0 + rb + r) * IMG_W + gj]);
        float yy[4] = {y4.x, y4.y, y4.z, y4.w};
        float pp[4], ee[4];
#pragma unroll
        for (int u = 0; u < 4; ++u) {
            float y  = yy[u];
            float E  = __expf(-fabsf(y));
            float tt = 1.0f + E;
            float rr = __fdividef(1.0f, tt);
            float p  = (y >= 0.0f) ? rr : E * rr;
            float sp = fmaxf(y, 0.0f) + __logf(tt);
            pp[u] = p;
            ee[u] = fmaf(fmaf(p, y, -sp), INV_LOG2, 1.0f);
        }
        pv4[r] = make_float4(pp[0], pp[1], pp[2], pp[3]);
        ev4[r] = make_float4(ee[0], ee[1], ee[2], ee[3]);
        *reinterpret_cast<float4*>(&pbuf[(HALO + rb + r) * LW + (HALO + c0i)]) =
            pv4[r];
    }

    // ---- stage (b): top/bottom halo rows {0,1,18,19}, interior cols.
    // 4 rows x 16 float4 = 64 slots -> one per lane. OOB rows -> p = 0.0
    // (the analytic C-1 normalization relies on OOB entries being zero).
    {
        int rsel = lane >> 4;                        // 0..3
        int pr   = (rsel < 2) ? rsel : (WTH + rsel); // 0,1,18,19
        int c4   = (lane & 15) << 2;
        int grow = wy0 - HALO + pr;
        bool inb = (unsigned)grow < (unsigned)IMG_H;
        float4 v = make_float4(0.f, 0.f, 0.f, 0.f);
        if (inb)
            v = *reinterpret_cast<const float4*>(
                &yimg[(size_t)grow * IMG_W + gj0 + c4]);
        float* d = &pbuf[pr * LW + HALO + c4];
        d[0] = inb ? fast_sigmoid(v.x) : 0.0f;
        d[1] = inb ? fast_sigmoid(v.y) : 0.0f;
        d[2] = inb ? fast_sigmoid(v.z) : 0.0f;
        d[3] = inb ? fast_sigmoid(v.w) : 0.0f;
    }

    // ---- stage (c): halo cols {0,1,66,67} x rows 0..19 = 80 px ----
    for (int idx = lane; idx < SROWS * 4; idx += 64) {
        int pr = idx >> 2;
        int h  = idx & 3;
        int pc = (h < 2) ? h : (TILE + h);           // 0,1,66,67
        int grow = wy0 - HALO + pr;
        int gcol = gj0 - HALO + pc;
        float p = 0.f;
        if ((unsigned)grow < (unsigned)IMG_H && (unsigned)gcol < (unsigned)IMG_W)
            p = fast_sigmoid(yimg[(size_t)grow * IMG_W + gcol]);
        pbuf[pr * LW + pc] = p;
    }

    __builtin_amdgcn_wave_barrier();   // scheduling fence (no hw cost)

    // ---- compute: vertical sliding 5-row window over pw cols c0i..c0i+7 ----
    float cxv[4], rcp5[4];
#pragma unroll
    for (int c = 0; c < 4; ++c) {
        int g = gj + c;
        cxv[c] = (float)(min(g, HALO) + min(IMG_W - 1 - g, HALO) + 1);
        rcp5[c] = __fdividef(1.0f, fmaf(5.0f, cxv[c], -1.0f));  // interior cy=5
    }

    float V1[8], V2[8];
#pragma unroll
    for (int cc = 0; cc < 8; ++cc) { V1[cc] = 0.f; V2[cc] = 0.f; }
#pragma unroll
    for (int k = 0; k < 5; ++k) {
        const float* row = &pbuf[(rb + k) * LW + c0i];
        float4 A = *reinterpret_cast<const float4*>(row);
        float4 B = *reinterpret_cast<const float4*>(row + 4);
        float a[8] = {A.x, A.y, A.z, A.w, B.x, B.y, B.z, B.w};
#pragma unroll
        for (int cc = 0; cc < 8; ++cc) {
            V1[cc] += a[cc];
            V2[cc] = fmaf(a[cc], a[cc], V2[cc]);
        }
    }

    float lsum = 0.0f;

#pragma unroll
    for (int r = 0; r < 4; ++r) {
        const int gi = wy0 + rb + r;   // <= 767

        float4 g4 = *reinterpret_cast<const float4*>(&gimg[(size_t)gi * IMG_W + gj]);

        // horizontal 5-window sums over the vertical column sums
        float t01 = V1[0] + V1[1], t12 = V1[1] + V1[2], t23 = V1[2] + V1[3];
        float t34 = V1[3] + V1[4], t45 = V1[4] + V1[5], t56 = V1[5] + V1[6];
        float S1v[4] = { t01 + t23 + V1[4], t12 + t34 + V1[5],
                         t23 + t45 + V1[6], t34 + t56 + V1[7] };
        float u01 = V2[0] + V2[1], u12 = V2[1] + V2[2], u23 = V2[2] + V2[3];
        float u34 = V2[3] + V2[4], u45 = V2[4] + V2[5], u56 = V2[5] + V2[6];
        float S2v[4] = { u01 + u23 + V2[4], u12 + u34 + V2[5],
                         u23 + u45 + V2[6], u34 + u56 + V2[7] };

        float cy = (float)(min(gi, HALO) + min(IMG_H - 1 - gi, HALO) + 1);
        float rc[4];
        if (cy == 5.0f) {
#pragma unroll
            for (int c = 0; c < 4; ++c) rc[c] = rcp5[c];
        } else {
#pragma unroll
            for (int c = 0; c < 4; ++c)
                rc[c] = __fdividef(1.0f, fmaf(cy, cxv[c], -1.0f));
        }

        float pcv[4] = {pv4[r].x, pv4[r].y, pv4[r].z, pv4[r].w};
        float ev[4]  = {ev4[r].x, ev4[r].y, ev4[r].z, ev4[r].w};
        float gv[4]  = {g4.x, g4.y, g4.z, g4.w};
        float wv[4];
#pragma unroll
        for (int c = 0; c < 4; ++c) {
            float pc = pcv[c];
            float C = cy * cxv[c];
            float acc = fmaf(C * pc, pc, fmaf(-2.0f * pc, S1v[c], S2v[c]));
            float cons = fmaf(-acc, rc[c], 1.0f);
            float w = fmaxf(cons * ev[c], gv[c]);
            w = fmaf(w, 0.9f, 0.1f);
            wv[c] = w;
            lsum += w;
        }
        *reinterpret_cast<float4*>(&oimg[(size_t)gi * IMG_W + gj]) =
            make_float4(wv[0], wv[1], wv[2], wv[3]);

        if (r < 3) {   // slide: add incoming pw row rb+r+5 (<=19), drop rb+r
            const float* rin  = &pbuf[(rb + r + 5) * LW + c0i];
            const float* rout = &pbuf[(rb + r) * LW + c0i];
            float4 IA = *reinterpret_cast<const float4*>(rin);
            float4 IB = *reinterpret_cast<const float4*>(rin + 4);
            float4 OA = *reinterpret_cast<const float4*>(rout);
            float4 OB = *reinterpret_cast<const float4*>(rout + 4);
            float vin[8]  = {IA.x, IA.y, IA.z, IA.w, IB.x, IB.y, IB.z, IB.w};
            float vout[8] = {OA.x, OA.y, OA.z, OA.w, OB.x, OB.y, OB.z, OB.w};
#pragma unroll
            for (int cc = 0; cc < 8; ++cc) {
                V1[cc] += vin[cc] - vout[cc];
                V2[cc] += fmaf(vin[cc], vin[cc], -(vout[cc] * vout[cc]));
            }
        }
    }

    // ---- per-image sum: wave shfl-reduce -> one atomic per wave ----
#pragma unroll
    for (int off = 32; off > 0; off >>= 1)
        lsum += __shfl_down(lsum, off, 64);
    if (lane == 0)
        atomicAdd(&sums[img], lsum);
}

// Pass 2: divide by per-image mean.
__global__ __launch_bounds__(256) void wk_pass2(
    float* __restrict__ out, const float* __restrict__ sums)
{
    const size_t total4 = (size_t)N_IMG * IMG_H * IMG_W / 4;
    const int per_img4 = IMG_H * IMG_W / 4;   // 147456
    for (size_t i = (size_t)blockIdx.x * blockDim.x + threadIdx.x; i < total4;
         i += (size_t)gridDim.x * blockDim.x) {
        int img = (int)(i / per_img4);
        float scale = (float)(IMG_H * IMG_W) / sums[img];
        float4 v = reinterpret_cast<float4*>(out)[i];
        v.x *= scale; v.y *= scale; v.z *= scale; v.w *= scale;
        reinterpret_cast<float4*>(out)[i] = v;
    }
}

extern "C" void kernel_launch(void* const* d_in, const int* in_sizes, int n_in,
                              void* d_out, int out_size, void* d_ws, size_t ws_size,
                              hipStream_t stream) {
    const float* y_d  = (const float*)d_in[0];
    const float* y_gt = (const float*)d_in[1];
    float* out  = (float*)d_out;
    float* sums = (float*)d_ws;

    hipMemsetAsync(sums, 0, N_IMG * sizeof(float), stream);

    const int tiles_per_img = (IMG_H / TILE) * (IMG_W / TILE);  // 144
    wk_pass1<<<dim3(N_IMG * tiles_per_img), dim3(256), 0, stream>>>(y_d, y_gt, out, sums);
    wk_pass2<<<dim3(2048), dim3(256), 0, stream>>>(out, sums);
}

// Round 10
// 94.753 us; speedup vs baseline: 2.4822x; 2.4822x over previous
//
#include <hip/hip_runtime.h>

#define IMG_H 768
#define IMG_W 768
#define N_IMG 32
#define TILE 64
#define HALO 2
#define LW 68              // 64 + 2*HALO
#define INV_LOG2 1.44269504088896340736f
#define TILES_X 12
#define TILES_PER_IMG 144
#define NTILES (N_IMG * TILES_PER_IMG)   // 4608
#define GRID1 1536                        // 3 tiles per block, exact

__device__ __forceinline__ float fast_sigmoid(float y) {
    return 1.0f / (1.0f + __expf(-y));
}

// Persistent-block pass 1: each block processes 3 tiles (round-8 body in a
// tile loop). Blocks launch once and stay resident -> dispatch ramp amortized.
__global__ __launch_bounds__(256) void wk_pass1(
    const float* __restrict__ y_d, const float* __restrict__ y_gt,
    float* __restrict__ out, float* __restrict__ sums)
{
    __shared__ float pbuf[LW * LW];   // 18.5 KB
    __shared__ float red[4];

    const int tid = threadIdx.x;
    const int c0 = (tid & 15) << 2;    // tile col base 0..60 (own block)
    const int rb = (tid >> 4) << 2;    // tile row base 0..60 (own block)

    for (int it = 0; it < 3; ++it) {
        const int tile = blockIdx.x + it * GRID1;      // < 4608
        const int img = tile / TILES_PER_IMG;
        const int t   = tile - img * TILES_PER_IMG;
        const int ti  = t / TILES_X;
        const int tj  = t - ti * TILES_X;
        const int gi0 = ti * TILE, gj0 = tj * TILE;

        const size_t img_off = (size_t)img * IMG_H * IMG_W;
        const float* __restrict__ yimg = y_d + img_off;
        const float* __restrict__ gimg = y_gt + img_off;
        float* __restrict__ oimg = out + img_off;
        const int gj = gj0 + c0;

        if (it > 0) __syncthreads();   // prev tile's pbuf readers done

        // ---- stage (a): own 4x4 block (always in-bounds). p -> LDS;
        // ent + p kept in registers. ent = 1 + (p*y - softplus(y))/ln2,
        // softplus = max(y,0)+log(1+e^-|y|) shares the exp with sigmoid.
        float4 yv4[4];
#pragma unroll
        for (int r = 0; r < 4; ++r)
            yv4[r] = *reinterpret_cast<const float4*>(
                &yimg[(size_t)(gi0 + rb + r) * IMG_W + gj]);

        float4 pv4[4], ev4[4];
#pragma unroll
        for (int r = 0; r < 4; ++r) {
            float yy[4] = {yv4[r].x, yv4[r].y, yv4[r].z, yv4[r].w};
            float pp[4], ee[4];
#pragma unroll
            for (int u = 0; u < 4; ++u) {
                float y  = yy[u];
                float E  = __expf(-fabsf(y));
                float tt = 1.0f + E;
                float rr = __fdividef(1.0f, tt);
                float p  = (y >= 0.0f) ? rr : E * rr;
                float sp = fmaxf(y, 0.0f) + __logf(tt);
                pp[u] = p;
                ee[u] = fmaf(fmaf(p, y, -sp), INV_LOG2, 1.0f);
            }
            pv4[r] = make_float4(pp[0], pp[1], pp[2], pp[3]);
            ev4[r] = make_float4(ee[0], ee[1], ee[2], ee[3]);
            *reinterpret_cast<float4*>(
                &pbuf[(rb + HALO + r) * LW + (c0 + HALO)]) = pv4[r];
        }

        // ---- stage (b): halo, p only. Rows {0,1,66,67} x 68 cols (272) +
        // cols {0,1,66,67} x rows 2..65 (256) = 528. OOB -> p = 0.0
        // (the analytic C-1 normalization relies on OOB entries being zero).
        for (int idx = tid; idx < 528; idx += 256) {
            int pr, pc;
            if (idx < 272) {
                int rsel = idx / 68;
                pr = (rsel < 2) ? rsel : (64 + rsel);    // 0,1,66,67
                pc = idx - rsel * 68;
            } else {
                int k = idx - 272;
                pr = (k >> 2) + 2;                       // 2..65
                int h = k & 3;
                pc = (h < 2) ? h : (64 + h);             // 0,1,66,67
            }
            int gi_ = gi0 - HALO + pr;
            int gj_ = gj0 - HALO + pc;
            float p = 0.f;
            if ((unsigned)gi_ < (unsigned)IMG_H && (unsigned)gj_ < (unsigned)IMG_W)
                p = fast_sigmoid(yimg[(size_t)gi_ * IMG_W + gj_]);
            pbuf[pr * LW + pc] = p;
        }
        __syncthreads();

        // ---- compute: vertical sliding 5-row window, cols c0..c0+7 ----
        float cxv[4], rcp5[4];
#pragma unroll
        for (int c = 0; c < 4; ++c) {
            int g = gj + c;
            cxv[c] = (float)(min(g, HALO) + min(IMG_W - 1 - g, HALO) + 1);
            rcp5[c] = __fdividef(1.0f, fmaf(5.0f, cxv[c], -1.0f)); // cy=5
        }

        float V1[8], V2[8];
#pragma unroll
        for (int cc = 0; cc < 8; ++cc) { V1[cc] = 0.f; V2[cc] = 0.f; }
#pragma unroll
        for (int k = 0; k < 5; ++k) {
            const float* row = &pbuf[(rb + k) * LW + c0];
            float4 A = *reinterpret_cast<const float4*>(row);
            float4 B = *reinterpret_cast<const float4*>(row + 4);
            float a[8] = {A.x, A.y, A.z, A.w, B.x, B.y, B.z, B.w};
#pragma unroll
            for (int cc = 0; cc < 8; ++cc) {
                V1[cc] += a[cc];
                V2[cc] = fmaf(a[cc], a[cc], V2[cc]);
            }
        }

        float lsum = 0.0f;

#pragma unroll
        for (int r = 0; r < 4; ++r) {
            const int gi = gi0 + rb + r;   // <= 767

            float4 g4 = *reinterpret_cast<const float4*>(
                &gimg[(size_t)gi * IMG_W + gj]);

            float t01 = V1[0] + V1[1], t12 = V1[1] + V1[2], t23 = V1[2] + V1[3];
            float t34 = V1[3] + V1[4], t45 = V1[4] + V1[5], t56 = V1[5] + V1[6];
            float S1v[4] = { t01 + t23 + V1[4], t12 + t34 + V1[5],
                             t23 + t45 + V1[6], t34 + t56 + V1[7] };
            float u01 = V2[0] + V2[1], u12 = V2[1] + V2[2], u23 = V2[2] + V2[3];
            float u34 = V2[3] + V2[4], u45 = V2[4] + V2[5], u56 = V2[5] + V2[6];
            float S2v[4] = { u01 + u23 + V2[4], u12 + u34 + V2[5],
                             u23 + u45 + V2[6], u34 + u56 + V2[7] };

            float cy = (float)(min(gi, HALO) + min(IMG_H - 1 - gi, HALO) + 1);
            float rc[4];
            if (cy == 5.0f) {
#pragma unroll
                for (int c = 0; c < 4; ++c) rc[c] = rcp5[c];
            } else {
#pragma unroll
                for (int c = 0; c < 4; ++c)
                    rc[c] = __fdividef(1.0f, fmaf(cy, cxv[c], -1.0f));
            }

            float pcv[4] = {pv4[r].x, pv4[r].y, pv4[r].z, pv4[r].w};
            float ev[4]  = {ev4[r].x, ev4[r].y, ev4[r].z, ev4[r].w};
            float gv[4]  = {g4.x, g4.y, g4.z, g4.w};
            float wv[4];
#pragma unroll
            for (int c = 0; c < 4; ++c) {
                float pc = pcv[c];
                float C = cy * cxv[c];
                float acc = fmaf(C * pc, pc, fmaf(-2.0f * pc, S1v[c], S2v[c]));
                float cons = fmaf(-acc, rc[c], 1.0f);
                float w = fmaxf(cons * ev[c], gv[c]);
                w = fmaf(w, 0.9f, 0.1f);
                wv[c] = w;
                lsum += w;
            }
            *reinterpret_cast<float4*>(&oimg[(size_t)gi * IMG_W + gj]) =
                make_float4(wv[0], wv[1], wv[2], wv[3]);

            if (r < 3) {   // slide: add row rb+r+5, remove row rb+r (LDS)
                const float* rin  = &pbuf[(rb + r + 5) * LW + c0];
                const float* rout = &pbuf[(rb + r) * LW + c0];
                float4 IA = *reinterpret_cast<const float4*>(rin);
                float4 IB = *reinterpret_cast<const float4*>(rin + 4);
                float4 OA = *reinterpret_cast<const float4*>(rout);
                float4 OB = *reinterpret_cast<const float4*>(rout + 4);
                float vin[8]  = {IA.x, IA.y, IA.z, IA.w, IB.x, IB.y, IB.z, IB.w};
                float vout[8] = {OA.x, OA.y, OA.z, OA.w, OB.x, OB.y, OB.z, OB.w};
#pragma unroll
                for (int cc = 0; cc < 8; ++cc) {
                    V1[cc] += vin[cc] - vout[cc];
                    V2[cc] += fmaf(vin[cc], vin[cc], -(vout[cc] * vout[cc]));
                }
            }
        }

        // ---- per-image sum: wave reduce -> LDS -> one atomic per tile ----
#pragma unroll
        for (int off = 32; off > 0; off >>= 1)
            lsum += __shfl_down(lsum, off, 64);
        if ((tid & 63) == 0) red[tid >> 6] = lsum;
        __syncthreads();
        if (tid == 0)
            atomicAdd(&sums[img], (red[0] + red[1]) + (red[2] + red[3]));
    }
}

// Pass 2: divide by per-image mean.
__global__ __launch_bounds__(256) void wk_pass2(
    float* __restrict__ out, const float* __restrict__ sums)
{
    const size_t total4 = (size_t)N_IMG * IMG_H * IMG_W / 4;
    const int per_img4 = IMG_H * IMG_W / 4;   // 147456
    for (size_t i = (size_t)blockIdx.x * blockDim.x + threadIdx.x; i < total4;
         i += (size_t)gridDim.x * blockDim.x) {
        int img = (int)(i / per_img4);
        float scale = (float)(IMG_H * IMG_W) / sums[img];
        float4 v = reinterpret_cast<float4*>(out)[i];
        v.x *= scale; v.y *= scale; v.z *= scale; v.w *= scale;
        reinterpret_cast<float4*>(out)[i] = v;
    }
}

extern "C" void kernel_launch(void* const* d_in, const int* in_sizes, int n_in,
                              void* d_out, int out_size, void* d_ws, size_t ws_size,
                              hipStream_t stream) {
    const float* y_d  = (const float*)d_in[0];
    const float* y_gt = (const float*)d_in[1];
    float* out  = (float*)d_out;
    float* sums = (float*)d_ws;

    hipMemsetAsync(sums, 0, N_IMG * sizeof(float), stream);

    wk_pass1<<<dim3(GRID1), dim3(256), 0, stream>>>(y_d, y_gt, out, sums);
    wk_pass2<<<dim3(2048), dim3(256), 0, stream>>>(out, sums);
}